// Round 1
// baseline (1041.369 us; speedup 1.0000x reference)
//
#include <hip/hip_runtime.h>
#include <hip/hip_bf16.h>
#include <math.h>

// Shapes (fixed by the problem)
#define Bb   64
#define Nn   40
#define Ww   256
#define FIN  64
#define Hh   4
#define Dd   32
#define Cc   128
#define NT   7
#define FC   128
#define WT   61          // timesteps needed: receptive field of TCN = 61
#define W0   195         // first needed global timestep (255-60)

__device__ __forceinline__ float gelu_exact(float v) {
    return 0.5f * v * (1.0f + erff(v * 0.70710678118654752440f));
}

// ---------------------------------------------------------------------------
// Kernel 1: per (b, tau) tile: h = x @ gat_w^T, attention (n<7 targets),
// LayerNorm, write seq[r][tau][c] for r = b*7+n.
// ---------------------------------------------------------------------------
__global__ __launch_bounds__(256) void gat_ln_kernel(
    const float* __restrict__ x, const float* __restrict__ adj,
    const float* __restrict__ gat_w, const float* __restrict__ a_src,
    const float* __restrict__ a_dst, const float* __restrict__ ln_g,
    const float* __restrict__ ln_b, float* __restrict__ seq)
{
    __shared__ __align__(16) float x_lds[Nn * FIN];      // 10 KB
    __shared__ __align__(16) float h_lds[Nn * Cc];       // 20 KB
    __shared__ __align__(16) float e_lds[2 * Nn * Hh];   // [src/dst][n][h]
    __shared__ __align__(16) float attn_lds[NT * Hh * Nn];
    __shared__ __align__(16) float g_lds[NT * Cc];

    const int tid = threadIdx.x;
    const int blk = blockIdx.x;
    const int b   = blk / WT;
    const int tau = blk % WT;
    const int w   = W0 + tau;

    // ---- load x[b, :, w, :] (40 x 64), coalesced ----
    for (int idx = tid; idx < Nn * FIN; idx += 256) {
        const int n = idx >> 6, f = idx & 63;
        x_lds[idx] = x[((b * Nn + n) * Ww + w) * FIN + f];
    }
    __syncthreads();

    // ---- h[n][co] = sum_f x[n][f] * gat_w[co][f] ----
    {
        const int co = tid & 127;
        const int nh = tid >> 7;
        float wreg[FIN];
        const float4* wr = (const float4*)(gat_w + co * FIN);
#pragma unroll
        for (int i = 0; i < FIN / 4; ++i) ((float4*)wreg)[i] = wr[i];
        for (int n = nh; n < Nn; n += 2) {
            const float4* xr = (const float4*)(x_lds + n * FIN);
            float acc = 0.f;
#pragma unroll
            for (int i = 0; i < FIN / 4; ++i) {
                const float4 xv = xr[i];
                acc += xv.x * wreg[4*i+0] + xv.y * wreg[4*i+1]
                     + xv.z * wreg[4*i+2] + xv.w * wreg[4*i+3];
            }
            h_lds[n * Cc + co] = acc;
        }
    }
    __syncthreads();

    // ---- e_src/e_dst[n][h] = sum_d h[n][h*32+d] * a[h][d] ----
    for (int idx = tid; idx < 2 * Nn * Hh; idx += 256) {
        const int s  = idx & 1;
        const int hh = (idx >> 1) & 3;
        const int n  = idx >> 3;
        const float* av = s ? a_dst : a_src;
        float acc = 0.f;
#pragma unroll
        for (int d = 0; d < Dd; ++d)
            acc += h_lds[n * Cc + hh * Dd + d] * av[hh * Dd + d];
        e_lds[s * (Nn * Hh) + n * Hh + hh] = acc;
    }
    __syncthreads();

    // ---- attention softmax for target nodes n<7, all 4 heads ----
    if (tid < NT * Hh) {
        const int n  = tid >> 2;
        const int hh = tid & 3;
        const float es = e_lds[n * Hh + hh];
        float sc[Nn];
        float mx = -1e30f;
#pragma unroll
        for (int j = 0; j < Nn; ++j) {
            float s = es + e_lds[Nn * Hh + j * Hh + hh];
            s = (s > 0.f) ? s : 0.2f * s;           // leaky_relu(0.2)
            if (adj[n * Nn + j] == 0.0f) s = -1e9f; // mask
            sc[j] = s;
            mx = fmaxf(mx, s);
        }
        float sum = 0.f;
#pragma unroll
        for (int j = 0; j < Nn; ++j) { const float p = expf(sc[j] - mx); sc[j] = p; sum += p; }
        const float inv = 1.0f / sum;
#pragma unroll
        for (int j = 0; j < Nn; ++j)
            attn_lds[(n * Hh + hh) * Nn + j] = sc[j] * inv;
    }
    __syncthreads();

    // ---- gat[n][c] = sum_j attn[n][h][j] * h[j][c]  (c = h*32+d) ----
    for (int idx = tid; idx < NT * Cc; idx += 256) {
        const int n  = idx >> 7;
        const int c  = idx & 127;
        const int hh = c >> 5;
        const float* ap = attn_lds + (n * Hh + hh) * Nn;
        float acc = 0.f;
#pragma unroll
        for (int j = 0; j < Nn; ++j)
            acc += ap[j] * h_lds[j * Cc + c];
        g_lds[idx] = acc;
    }
    __syncthreads();

    // ---- LayerNorm over C + write seq[(b*7+n)][tau][c] ----
    if (tid < NT * 32) {
        const int n = tid >> 5, lane = tid & 31;
        const float4 v = ((const float4*)(g_lds + n * Cc))[lane];
        float s  = v.x + v.y + v.z + v.w;
        float sq = v.x*v.x + v.y*v.y + v.z*v.z + v.w*v.w;
#pragma unroll
        for (int off = 16; off; off >>= 1) {
            s  += __shfl_xor(s, off, 32);
            sq += __shfl_xor(sq, off, 32);
        }
        const float mu   = s * (1.0f / Cc);
        const float rstd = rsqrtf(sq * (1.0f / Cc) - mu * mu + 1e-5f);
        const float4 gg = ((const float4*)ln_g)[lane];
        const float4 bb = ((const float4*)ln_b)[lane];
        float4 o;
        o.x = (v.x - mu) * rstd * gg.x + bb.x;
        o.y = (v.y - mu) * rstd * gg.y + bb.y;
        o.z = (v.z - mu) * rstd * gg.z + bb.z;
        o.w = (v.w - mu) * rstd * gg.w + bb.w;
        const int r = b * NT + n;
        ((float4*)(seq + (r * WT + tau) * Cc))[lane] = o;
    }
}

// ---------------------------------------------------------------------------
// Kernel 2: per row r (448 rows): 4-level TCN entirely in LDS + fused head.
// thread: co = tid&127, half = tid>>7 handles taus {tau0+half, +2, ...}
// ---------------------------------------------------------------------------
__device__ __forceinline__ void conv_phase(
    const float* in_lds, float* out_lds,
    const float* __restrict__ wrow,      // global, 384 floats for this co
    const float bias, const float scale, const float shift,
    const int tau0, const int d, const int co, const int half,
    const bool residual)
{
    const int tstart = tau0 + half;                 // tau_t = tstart + 2t
    const int cnt = (tstart > 60) ? 0 : ((60 - tstart) >> 1) + 1;
    const int d2 = 2 * d;

    float acc[32];
#pragma unroll
    for (int t = 0; t < 32; ++t) acc[t] = 0.f;

    const float4* wp0 = (const float4*)wrow;
    float4 wa = wp0[0], wb = wp0[1], wc = wp0[2];
    for (int ci = 0; ci < Cc; ci += 4) {
        float4 na, nb, nc;
        if (ci + 4 < Cc) {                           // prefetch next weights
            const float4* np = (const float4*)(wrow + (ci + 4) * 3);
            na = np[0]; nb = np[1]; nc = np[2];
        }
        const float* base = in_lds + ci;
#pragma unroll
        for (int t = 0; t < 32; ++t) {
            if (t < cnt) {
                const int tau = tstart + 2 * t;
                const float4 i0 = *(const float4*)(base + (tau - d2) * Cc);
                const float4 i1 = *(const float4*)(base + (tau - d ) * Cc);
                const float4 i2 = *(const float4*)(base + (tau     ) * Cc);
                acc[t] += wa.x * i0.x + wa.y * i1.x + wa.z * i2.x
                        + wa.w * i0.y + wb.x * i1.y + wb.y * i2.y
                        + wb.z * i0.z + wb.w * i1.z + wc.x * i2.z
                        + wc.y * i0.w + wc.z * i1.w + wc.w * i2.w;
            }
        }
        wa = na; wb = nb; wc = nc;
    }

#pragma unroll
    for (int t = 0; t < 32; ++t) {
        if (t < cnt) {
            const int tau = tstart + 2 * t;
            float v = (acc[t] + bias) * scale + shift;   // BN folded
            v = gelu_exact(v);
            if (residual) v = gelu_exact(v + out_lds[tau * Cc + co]);
            out_lds[tau * Cc + co] = v;
        }
    }
}

__global__ __launch_bounds__(256) void tcn_head_kernel(
    const float* __restrict__ seq,
    const float* __restrict__ c1w, const float* __restrict__ c1b,
    const float* __restrict__ c2w, const float* __restrict__ c2b,
    const float* __restrict__ bn1s, const float* __restrict__ bn1b,
    const float* __restrict__ bn1m, const float* __restrict__ bn1v,
    const float* __restrict__ bn2s, const float* __restrict__ bn2b,
    const float* __restrict__ bn2m, const float* __restrict__ bn2v,
    const float* __restrict__ f1w, const float* __restrict__ f1b,
    const float* __restrict__ f2w, const float* __restrict__ f2b,
    float* __restrict__ out)
{
    __shared__ __align__(16) float cur[WT * Cc];   // 31.2 KB
    __shared__ __align__(16) float o1 [WT * Cc];   // 31.2 KB
    __shared__ __align__(16) float red[FC];

    const int tid = threadIdx.x;
    const int r   = blockIdx.x;

    // load seq row (61 x 128) into cur, coalesced float4
    {
        const float4* src = (const float4*)(seq + r * WT * Cc);
        float4* dst = (float4*)cur;
        for (int i = tid; i < WT * Cc / 4; i += 256) dst[i] = src[i];
    }
    __syncthreads();

    const int co   = tid & 127;
    const int half = tid >> 7;

    int vstart = 0;
    for (int l = 0; l < 4; ++l) {
        const int d = 1 << l;
        const int lc = l * Cc + co;
        // conv1 -> o1
        {
            const float sc1 = bn1s[lc] * rsqrtf(bn1v[lc] + 1e-5f);
            const float sh1 = bn1b[lc] - bn1m[lc] * sc1;
            conv_phase(cur, o1, c1w + (size_t)lc * (Cc * 3), c1b[lc],
                       sc1, sh1, vstart + 2 * d, d, co, half, false);
        }
        __syncthreads();
        // conv2 + residual -> cur (in place)
        {
            const float sc2 = bn2s[lc] * rsqrtf(bn2v[lc] + 1e-5f);
            const float sh2 = bn2b[lc] - bn2m[lc] * sc2;
            conv_phase(o1, cur, c2w + (size_t)lc * (Cc * 3), c2b[lc],
                       sc2, sh2, vstart + 4 * d, d, co, half, true);
        }
        __syncthreads();
        vstart += 4 * d;
    }

    // ---- head: z_h = gelu(f1w[h] . h_last + f1b[h]);  out = sum z_h*f2w[h] + f2b
    if (tid < FC) {
        const float4* wr = (const float4*)(f1w + tid * Cc);
        const float4* hv = (const float4*)(cur + 60 * Cc);
        float acc = 0.f;
#pragma unroll
        for (int i = 0; i < Cc / 4; ++i) {
            const float4 wv = wr[i];
            const float4 xv = hv[i];
            acc += wv.x * xv.x + wv.y * xv.y + wv.z * xv.z + wv.w * xv.w;
        }
        red[tid] = gelu_exact(acc + f1b[tid]) * f2w[tid];
    }
    __syncthreads();
    if (tid < 64) {
        float v = red[tid] + red[tid + 64];
#pragma unroll
        for (int off = 32; off; off >>= 1) v += __shfl_xor(v, off, 64);
        if (tid == 0) out[r] = v + f2b[0];
    }
}

// ---------------------------------------------------------------------------
extern "C" void kernel_launch(void* const* d_in, const int* in_sizes, int n_in,
                              void* d_out, int out_size, void* d_ws, size_t ws_size,
                              hipStream_t stream) {
    const float* x     = (const float*)d_in[0];
    const float* adj   = (const float*)d_in[1];
    const float* gat_w = (const float*)d_in[2];
    const float* a_src = (const float*)d_in[3];
    const float* a_dst = (const float*)d_in[4];
    const float* ln_g  = (const float*)d_in[5];
    const float* ln_b  = (const float*)d_in[6];
    const float* c1w   = (const float*)d_in[7];
    const float* c1b   = (const float*)d_in[8];
    const float* c2w   = (const float*)d_in[9];
    const float* c2b   = (const float*)d_in[10];
    const float* bn1s  = (const float*)d_in[11];
    const float* bn1b  = (const float*)d_in[12];
    const float* bn1m  = (const float*)d_in[13];
    const float* bn1v  = (const float*)d_in[14];
    const float* bn2s  = (const float*)d_in[15];
    const float* bn2b  = (const float*)d_in[16];
    const float* bn2m  = (const float*)d_in[17];
    const float* bn2v  = (const float*)d_in[18];
    const float* f1w   = (const float*)d_in[19];
    const float* f1b   = (const float*)d_in[20];
    const float* f2w   = (const float*)d_in[21];
    const float* f2b   = (const float*)d_in[22];

    float* seq = (float*)d_ws;   // 448 * 61 * 128 floats = 13.97 MB

    gat_ln_kernel<<<Bb * WT, 256, 0, stream>>>(
        x, adj, gat_w, a_src, a_dst, ln_g, ln_b, seq);

    tcn_head_kernel<<<Bb * NT, 256, 0, stream>>>(
        seq, c1w, c1b, c2w, c2b,
        bn1s, bn1b, bn1m, bn1v, bn2s, bn2b, bn2m, bn2v,
        f1w, f1b, f2w, f2b, (float*)d_out);
}

// Round 2
// 761.013 us; speedup vs baseline: 1.3684x; 1.3684x over previous
//
#include <hip/hip_runtime.h>
#include <hip/hip_bf16.h>
#include <math.h>

// Shapes (fixed by the problem)
#define Bb   64
#define Nn   40
#define Ww   256
#define FIN  64
#define Hh   4
#define Dd   32
#define Cc   128
#define NT   7
#define FC   128
#define WT   61          // receptive field of the TCN stack
#define W0   195         // first needed global timestep (255-60)

// workspace layout (float offsets)
#define SEQ_OFF   0
#define SEQ_SZ    (448 * WT * Cc)          // 3,497,984 floats
#define WP_OFF    (SEQ_OFF + SEQ_SZ)       // permuted weights
#define WP_SZ     (8 * 32 * 12 * 32 * 4)   // 393,216 floats (8 phases)
#define BIAS_OFF  (WP_OFF + WP_SZ)
#define SCALE_OFF (BIAS_OFF + 1024)
#define SHIFT_OFF (SCALE_OFF + 1024)
#define PHASE_F4  (32 * 12 * 32)           // float4s per phase

__device__ __forceinline__ float gelu_exact(float v) {
    return 0.5f * v * (1.0f + erff(v * 0.70710678118654752440f));
}

// ---------------------------------------------------------------------------
// Prep: permute conv weights to [phase][cig][j=co_i*3+k][quad] float4(ci_i)
// so K2's weight loads are lane-coalesced; fold BN into scale/shift/bias.
// ---------------------------------------------------------------------------
__global__ __launch_bounds__(256) void prep_kernel(
    const float* __restrict__ c1w, const float* __restrict__ c1b,
    const float* __restrict__ c2w, const float* __restrict__ c2b,
    const float* __restrict__ bn1s, const float* __restrict__ bn1b,
    const float* __restrict__ bn1m, const float* __restrict__ bn1v,
    const float* __restrict__ bn2s, const float* __restrict__ bn2b,
    const float* __restrict__ bn2m, const float* __restrict__ bn2v,
    float* __restrict__ ws)
{
    if (blockIdx.x < 384) {
        const int idx = blockIdx.x * 256 + threadIdx.x;   // [0, 98304) float4s
        const int q   = idx & 31;
        const int t1  = idx >> 5;
        const int j   = t1 % 12;
        const int t2  = t1 / 12;
        const int cig = t2 & 31;
        const int p   = t2 >> 5;
        const int l   = p >> 1, cv = p & 1;
        const int co_i = j / 3, k = j % 3;
        const int co  = q * 4 + co_i;
        const float* wsrc = cv ? c2w : c1w;
        const float* r = wsrc + ((size_t)(l * Cc + co) * Cc + cig * 4) * 3 + k;
        float4 v;
        v.x = r[0]; v.y = r[3]; v.z = r[6]; v.w = r[9];
        ((float4*)(ws + WP_OFF))[idx] = v;
    } else {
        for (int idx = threadIdx.x; idx < 1024; idx += 256) {
            const int p = idx >> 7, co = idx & 127;
            const int l = p >> 1, cv = p & 1;
            const int lc = l * Cc + co;
            const float s  = cv ? bn2s[lc] : bn1s[lc];
            const float bb = cv ? bn2b[lc] : bn1b[lc];
            const float m  = cv ? bn2m[lc] : bn1m[lc];
            const float vv = cv ? bn2v[lc] : bn1v[lc];
            const float cb = cv ? c2b[lc] : c1b[lc];
            const float scale = s * rsqrtf(vv + 1e-5f);
            ws[SCALE_OFF + idx] = scale;
            ws[SHIFT_OFF + idx] = bb - m * scale;
            ws[BIAS_OFF  + idx] = cb;
        }
    }
}

// ---------------------------------------------------------------------------
// Kernel 1: per (b, tau): h = x @ gat_w^T (2 co/thread, e fused via shuffle),
// attention softmax (n<7), aggregation, LayerNorm, write seq.
// ---------------------------------------------------------------------------
__global__ __launch_bounds__(256) void gat_ln_kernel(
    const float* __restrict__ x, const float* __restrict__ adj,
    const float* __restrict__ gat_w, const float* __restrict__ a_src,
    const float* __restrict__ a_dst, const float* __restrict__ ln_g,
    const float* __restrict__ ln_b, float* __restrict__ seq)
{
    __shared__ __align__(16) float x_lds[Nn * FIN];
    __shared__ __align__(16) float h_lds[Nn * Cc];
    __shared__ __align__(16) float e_lds[2 * Nn * Hh];     // [src/dst][n][h]
    __shared__ __align__(16) float attn_lds[NT * Hh * Nn];
    __shared__ __align__(16) float g_lds[NT * Cc];

    const int tid = threadIdx.x;
    const int blk = blockIdx.x;
    const int b   = blk / WT;
    const int tau = blk % WT;
    const int w   = W0 + tau;

    // ---- load x[b, :, w, :] (40 x 64), coalesced ----
    for (int idx = tid; idx < Nn * FIN; idx += 256) {
        const int n = idx >> 6, f = idx & 63;
        x_lds[idx] = x[((b * Nn + n) * Ww + w) * FIN + f];
    }
    __syncthreads();

    // ---- h-GEMM, 2 co per thread; one wave covers all 128 co for its n ----
    {
        const int q   = tid & 63;        // co pair: lanes == q within a wave
        const int nh  = tid >> 6;        // 4 n-stripes, one per wave
        const int co0 = 2 * q, co1 = co0 + 1;
        float w0[FIN], w1[FIN];
        {
            const float4* wr0 = (const float4*)(gat_w + co0 * FIN);
            const float4* wr1 = (const float4*)(gat_w + co1 * FIN);
#pragma unroll
            for (int i = 0; i < FIN / 4; ++i) {
                ((float4*)w0)[i] = wr0[i];
                ((float4*)w1)[i] = wr1[i];
            }
        }
        const float as0 = a_src[co0], as1 = a_src[co1];
        const float ad0 = a_dst[co0], ad1 = a_dst[co1];
        for (int n = nh; n < Nn; n += 4) {
            const float4* xr = (const float4*)(x_lds + n * FIN);
            float a0 = 0.f, a1 = 0.f;
#pragma unroll
            for (int i = 0; i < FIN / 4; ++i) {
                const float4 xv = xr[i];
                a0 += xv.x * w0[4*i] + xv.y * w0[4*i+1] + xv.z * w0[4*i+2] + xv.w * w0[4*i+3];
                a1 += xv.x * w1[4*i] + xv.y * w1[4*i+1] + xv.z * w1[4*i+2] + xv.w * w1[4*i+3];
            }
            *(float2*)(h_lds + n * Cc + co0) = make_float2(a0, a1);
            // fused e reduction: head = co0>>5 = q>>4 -> groups of 16 lanes
            float es = a0 * as0 + a1 * as1;
            float ed = a0 * ad0 + a1 * ad1;
#pragma unroll
            for (int off = 1; off < 16; off <<= 1) {
                es += __shfl_xor(es, off, 16);
                ed += __shfl_xor(ed, off, 16);
            }
            if ((q & 15) == 0) {
                const int head = q >> 4;
                e_lds[n * Hh + head]           = es;
                e_lds[Nn * Hh + n * Hh + head] = ed;
            }
        }
    }
    __syncthreads();

    // ---- attention softmax for target nodes n<7, all 4 heads ----
    if (tid < NT * Hh) {
        const int n  = tid >> 2;
        const int hh = tid & 3;
        const float es = e_lds[n * Hh + hh];
        float sc[Nn];
        float mx = -1e30f;
#pragma unroll
        for (int j = 0; j < Nn; ++j) {
            float s = es + e_lds[Nn * Hh + j * Hh + hh];
            s = (s > 0.f) ? s : 0.2f * s;
            if (adj[n * Nn + j] == 0.0f) s = -1e9f;
            sc[j] = s;
            mx = fmaxf(mx, s);
        }
        float sum = 0.f;
#pragma unroll
        for (int j = 0; j < Nn; ++j) { const float p = expf(sc[j] - mx); sc[j] = p; sum += p; }
        const float inv = 1.0f / sum;
#pragma unroll
        for (int j = 0; j < Nn; ++j)
            attn_lds[(n * Hh + hh) * Nn + j] = sc[j] * inv;
    }
    __syncthreads();

    // ---- gat[n][c] = sum_j attn[n][h][j] * h[j][c] ----
    for (int idx = tid; idx < NT * Cc; idx += 256) {
        const int n  = idx >> 7;
        const int c  = idx & 127;
        const int hh = c >> 5;
        const float* ap = attn_lds + (n * Hh + hh) * Nn;
        float acc = 0.f;
#pragma unroll
        for (int j = 0; j < Nn; ++j)
            acc += ap[j] * h_lds[j * Cc + c];
        g_lds[idx] = acc;
    }
    __syncthreads();

    // ---- LayerNorm + write seq ----
    if (tid < NT * 32) {
        const int n = tid >> 5, lane = tid & 31;
        const float4 v = ((const float4*)(g_lds + n * Cc))[lane];
        float s  = v.x + v.y + v.z + v.w;
        float sq = v.x*v.x + v.y*v.y + v.z*v.z + v.w*v.w;
#pragma unroll
        for (int off = 16; off; off >>= 1) {
            s  += __shfl_xor(s, off, 32);
            sq += __shfl_xor(sq, off, 32);
        }
        const float mu   = s * (1.0f / Cc);
        const float rstd = rsqrtf(sq * (1.0f / Cc) - mu * mu + 1e-5f);
        const float4 gg = ((const float4*)ln_g)[lane];
        const float4 bb = ((const float4*)ln_b)[lane];
        float4 o;
        o.x = (v.x - mu) * rstd * gg.x + bb.x;
        o.y = (v.y - mu) * rstd * gg.y + bb.y;
        o.z = (v.z - mu) * rstd * gg.z + bb.z;
        o.w = (v.w - mu) * rstd * gg.w + bb.w;
        const int r = b * NT + n;
        ((float4*)(seq + (r * WT + tau) * Cc))[lane] = o;
    }
}

// ---------------------------------------------------------------------------
// Kernel 2: per row r: TCN in LDS, 4 co per thread, 512 threads.
// quad = tid&31 (co = 4*quad..+3), half = tid>>5 (tau stride 16).
// One wave covers all 128 co x 2 taus -> 3 ds_read_b128 feed 48 lane-FMAs x4ci.
// ---------------------------------------------------------------------------
__device__ __forceinline__ void conv_phase4(
    const float* __restrict__ in_lds, float* __restrict__ out_lds,
    const float4* __restrict__ wp,      // this phase's permuted weights
    const float4 b4, const float4 s4, const float4 h4,
    const int tau0, const int d, const int quad, const int half,
    const bool residual)
{
    const int tstart = tau0 + half;
    const int cnt = (tstart > 60) ? 0 : (((60 - tstart) >> 4) + 1);  // <= 4

    float acc[4][4];
#pragma unroll
    for (int c = 0; c < 4; ++c)
#pragma unroll
        for (int t = 0; t < 4; ++t) acc[c][t] = 0.f;

    if (cnt > 0) {
        const float* base0 = in_lds + (tstart - 2 * d) * Cc;
        const float* base1 = in_lds + (tstart -     d) * Cc;
        const float* base2 = in_lds + (tstart        ) * Cc;
        const float4* wq = wp + quad;
        for (int cig = 0; cig < 32; ++cig) {
            float4 wv[12];
#pragma unroll
            for (int j = 0; j < 12; ++j) wv[j] = wq[j * 32];   // coalesced
            wq += 12 * 32;
            const int cio = cig * 4;
#pragma unroll
            for (int t = 0; t < 4; ++t) {
                if (t < cnt) {
                    const int to = t * 16 * Cc + cio;
                    const float4 i0 = *(const float4*)(base0 + to);
                    const float4 i1 = *(const float4*)(base1 + to);
                    const float4 i2 = *(const float4*)(base2 + to);
#pragma unroll
                    for (int c = 0; c < 4; ++c) {
                        const float4 wa = wv[c*3+0], wb = wv[c*3+1], wc = wv[c*3+2];
                        acc[c][t] += wa.x*i0.x + wa.y*i0.y + wa.z*i0.z + wa.w*i0.w
                                   + wb.x*i1.x + wb.y*i1.y + wb.z*i1.z + wb.w*i1.w
                                   + wc.x*i2.x + wc.y*i2.y + wc.z*i2.z + wc.w*i2.w;
                    }
                }
            }
        }
    }

#pragma unroll
    for (int t = 0; t < 4; ++t) {
        if (t < cnt) {
            const int tau = tstart + 16 * t;
            float4 v;
            v.x = gelu_exact((acc[0][t] + b4.x) * s4.x + h4.x);
            v.y = gelu_exact((acc[1][t] + b4.y) * s4.y + h4.y);
            v.z = gelu_exact((acc[2][t] + b4.z) * s4.z + h4.z);
            v.w = gelu_exact((acc[3][t] + b4.w) * s4.w + h4.w);
            float* op = out_lds + tau * Cc + quad * 4;
            if (residual) {
                const float4 rr = *(const float4*)op;
                v.x = gelu_exact(v.x + rr.x);
                v.y = gelu_exact(v.y + rr.y);
                v.z = gelu_exact(v.z + rr.z);
                v.w = gelu_exact(v.w + rr.w);
            }
            *(float4*)op = v;
        }
    }
}

__global__ __launch_bounds__(512) void tcn_head_kernel(
    const float* __restrict__ ws,
    const float* __restrict__ f1w, const float* __restrict__ f1b,
    const float* __restrict__ f2w, const float* __restrict__ f2b,
    float* __restrict__ out)
{
    __shared__ __align__(16) float cur[WT * Cc];
    __shared__ __align__(16) float o1 [WT * Cc];
    __shared__ __align__(16) float red[FC];

    const int tid = threadIdx.x;
    const int r   = blockIdx.x;
    const float* seq = ws + SEQ_OFF;

    {
        const float4* src = (const float4*)(seq + (size_t)r * WT * Cc);
        float4* dst = (float4*)cur;
        for (int i = tid; i < WT * Cc / 4; i += 512) dst[i] = src[i];
    }
    __syncthreads();

    const int quad = tid & 31;
    const int half = tid >> 5;
    const float4* wp_all = (const float4*)(ws + WP_OFF);

    int vstart = 0;
    for (int l = 0; l < 4; ++l) {
        const int d  = 1 << l;
        const int p1 = l * 2, p2 = l * 2 + 1;
        {
            const float4 b4 = *(const float4*)(ws + BIAS_OFF  + p1 * Cc + quad * 4);
            const float4 s4 = *(const float4*)(ws + SCALE_OFF + p1 * Cc + quad * 4);
            const float4 h4 = *(const float4*)(ws + SHIFT_OFF + p1 * Cc + quad * 4);
            conv_phase4(cur, o1, wp_all + (size_t)p1 * PHASE_F4, b4, s4, h4,
                        vstart + 2 * d, d, quad, half, false);
        }
        __syncthreads();
        {
            const float4 b4 = *(const float4*)(ws + BIAS_OFF  + p2 * Cc + quad * 4);
            const float4 s4 = *(const float4*)(ws + SCALE_OFF + p2 * Cc + quad * 4);
            const float4 h4 = *(const float4*)(ws + SHIFT_OFF + p2 * Cc + quad * 4);
            conv_phase4(o1, cur, wp_all + (size_t)p2 * PHASE_F4, b4, s4, h4,
                        vstart + 4 * d, d, quad, half, true);
        }
        __syncthreads();
        vstart += 4 * d;
    }

    // ---- fused head ----
    if (tid < FC) {
        const float4* wr = (const float4*)(f1w + tid * Cc);
        const float4* hv = (const float4*)(cur + 60 * Cc);
        float acc = 0.f;
#pragma unroll
        for (int i = 0; i < Cc / 4; ++i) {
            const float4 wv = wr[i];
            const float4 xv = hv[i];
            acc += wv.x * xv.x + wv.y * xv.y + wv.z * xv.z + wv.w * xv.w;
        }
        red[tid] = gelu_exact(acc + f1b[tid]) * f2w[tid];
    }
    __syncthreads();
    if (tid < 64) {
        float v = red[tid] + red[tid + 64];
#pragma unroll
        for (int off = 32; off; off >>= 1) v += __shfl_xor(v, off, 64);
        if (tid == 0) out[r] = v + f2b[0];
    }
}

// ---------------------------------------------------------------------------
extern "C" void kernel_launch(void* const* d_in, const int* in_sizes, int n_in,
                              void* d_out, int out_size, void* d_ws, size_t ws_size,
                              hipStream_t stream) {
    const float* x     = (const float*)d_in[0];
    const float* adj   = (const float*)d_in[1];
    const float* gat_w = (const float*)d_in[2];
    const float* a_src = (const float*)d_in[3];
    const float* a_dst = (const float*)d_in[4];
    const float* ln_g  = (const float*)d_in[5];
    const float* ln_b  = (const float*)d_in[6];
    const float* c1w   = (const float*)d_in[7];
    const float* c1b   = (const float*)d_in[8];
    const float* c2w   = (const float*)d_in[9];
    const float* c2b   = (const float*)d_in[10];
    const float* bn1s  = (const float*)d_in[11];
    const float* bn1b  = (const float*)d_in[12];
    const float* bn1m  = (const float*)d_in[13];
    const float* bn1v  = (const float*)d_in[14];
    const float* bn2s  = (const float*)d_in[15];
    const float* bn2b  = (const float*)d_in[16];
    const float* bn2m  = (const float*)d_in[17];
    const float* bn2v  = (const float*)d_in[18];
    const float* f1w   = (const float*)d_in[19];
    const float* f1b   = (const float*)d_in[20];
    const float* f2w   = (const float*)d_in[21];
    const float* f2b   = (const float*)d_in[22];

    float* ws = (float*)d_ws;

    prep_kernel<<<385, 256, 0, stream>>>(c1w, c1b, c2w, c2b,
        bn1s, bn1b, bn1m, bn1v, bn2s, bn2b, bn2m, bn2v, ws);

    gat_ln_kernel<<<Bb * WT, 256, 0, stream>>>(
        x, adj, gat_w, a_src, a_dst, ln_g, ln_b, ws + SEQ_OFF);

    tcn_head_kernel<<<Bb * NT, 512, 0, stream>>>(
        ws, f1w, f1b, f2w, f2b, (float*)d_out);
}

// Round 3
// 449.056 us; speedup vs baseline: 2.3190x; 1.6947x over previous
//
#include <hip/hip_runtime.h>
#include <hip/hip_bf16.h>
#include <math.h>

// Shapes (fixed by the problem)
#define Bb   64
#define Nn   40
#define Ww   256
#define FIN  64
#define Hh   4
#define Dd   32
#define Cc   128
#define NT   7
#define FC   128
#define WT   61          // receptive field of the TCN stack
#define W0   195         // first needed global timestep (255-60)
#define RS   136         // LDS row stride (ushorts) = 272B -> 4-way not 16-way

// workspace layout (byte offsets). seq stored as split bf16 (hi+lo).
#define SEQHI_OFF  0u
#define SEQ_BYTES  (448u * WT * Cc * 2u)             // 6,995,968 B
#define SEQLO_OFF  (SEQHI_OFF + SEQ_BYTES)
#define WBH_OFF    (SEQLO_OFF + SEQ_BYTES)           // frag-ordered bf16 weights (hi)
#define WB_BYTES   (8u * 4u * 24u * 64u * 8u * 2u)   // 786,432 B
#define WBL_OFF    (WBH_OFF + WB_BYTES)
#define PSB_OFF    (WBL_OFF + WB_BYTES)              // f32 bias[8][128]
#define PSS_OFF    (PSB_OFF + 4096u)                 // f32 scale[8][128]
#define PSH_OFF    (PSS_OFF + 4096u)                 // f32 shift[8][128]
#define WPHASE_US  49152u                            // ushorts per phase in WBH/WBL

typedef __attribute__((ext_vector_type(8)))  short short8;
typedef __attribute__((ext_vector_type(16))) float f32x16;

__device__ __forceinline__ float gelu_exact(float v) {
    return 0.5f * v * (1.0f + erff(v * 0.70710678118654752440f));
}
__device__ __forceinline__ float b2f(ushort u) {
    union { uint i; float f; } c; c.i = ((uint)u) << 16; return c.f;
}
__device__ __forceinline__ void split_bf16(float v, ushort& h, ushort& l) {
    __hip_bfloat16 bh = __float2bfloat16(v);
    float fh = __bfloat162float(bh);
    __hip_bfloat16 bl = __float2bfloat16(v - fh);
    h = *(ushort*)&bh; l = *(ushort*)&bl;
}

// ---------------------------------------------------------------------------
// Prep: split conv weights into bf16 hi/lo in MFMA-B-fragment order
//   chunk t in [0,49152): lane=t&63, kstep=(t>>6)%24, nt=(t>>6)/24%4, p=(t>>6)/96
//   element j: k=kstep*16+(lane>>5)*8+j -> kk=k>>7, ci=k&127; co=nt*32+(lane&31)
// plus BN fold (bias/scale/shift per phase,co).
// ---------------------------------------------------------------------------
__global__ __launch_bounds__(256) void prep_kernel(
    const float* __restrict__ c1w, const float* __restrict__ c1b,
    const float* __restrict__ c2w, const float* __restrict__ c2b,
    const float* __restrict__ bn1s, const float* __restrict__ bn1b,
    const float* __restrict__ bn1m, const float* __restrict__ bn1v,
    const float* __restrict__ bn2s, const float* __restrict__ bn2b,
    const float* __restrict__ bn2m, const float* __restrict__ bn2v,
    char* __restrict__ ws)
{
    if (blockIdx.x < 192) {
        const int t = blockIdx.x * 256 + threadIdx.x;   // [0, 49152)
        const int lane  = t & 63;
        const int kstep = (t >> 6) % 24;
        const int nt    = ((t >> 6) / 24) & 3;
        const int p     = (t >> 6) / 96;
        const int l = p >> 1, cv = p & 1;
        const int co = nt * 32 + (lane & 31);
        const float* wsrc = cv ? c2w : c1w;
        ushort* wbh = (ushort*)(ws + WBH_OFF);
        ushort* wbl = (ushort*)(ws + WBL_OFF);
#pragma unroll
        for (int j = 0; j < 8; ++j) {
            const int k  = kstep * 16 + ((lane >> 5) << 3) + j;
            const int kk = k >> 7, ci = k & 127;
            const float w = wsrc[((size_t)(l * Cc + co) * Cc + ci) * 3 + kk];
            ushort h, lo; split_bf16(w, h, lo);
            wbh[(size_t)t * 8 + j] = h;
            wbl[(size_t)t * 8 + j] = lo;
        }
    } else {
        float* psb = (float*)(ws + PSB_OFF);
        float* pss = (float*)(ws + PSS_OFF);
        float* psh = (float*)(ws + PSH_OFF);
        for (int idx = threadIdx.x; idx < 1024; idx += 256) {
            const int p = idx >> 7, co = idx & 127;
            const int l = p >> 1, cv = p & 1;
            const int lc = l * Cc + co;
            const float s  = cv ? bn2s[lc] : bn1s[lc];
            const float bb = cv ? bn2b[lc] : bn1b[lc];
            const float m  = cv ? bn2m[lc] : bn1m[lc];
            const float vv = cv ? bn2v[lc] : bn1v[lc];
            const float cb = cv ? c2b[lc] : c1b[lc];
            const float scale = s * rsqrtf(vv + 1e-5f);
            pss[idx] = scale;
            psh[idx] = bb - m * scale;
            psb[idx] = cb;
        }
    }
}

// ---------------------------------------------------------------------------
// Kernel 1: per (b, tau): GAT + LayerNorm, write seq as split bf16.
// ---------------------------------------------------------------------------
__global__ __launch_bounds__(256) void gat_ln_kernel(
    const float* __restrict__ x, const float* __restrict__ adj,
    const float* __restrict__ gat_w, const float* __restrict__ a_src,
    const float* __restrict__ a_dst, const float* __restrict__ ln_g,
    const float* __restrict__ ln_b,
    ushort* __restrict__ seq_hi, ushort* __restrict__ seq_lo)
{
    __shared__ __align__(16) float x_lds[Nn * FIN];
    __shared__ __align__(16) float h_lds[Nn * Cc];
    __shared__ __align__(16) float e_lds[2 * Nn * Hh];
    __shared__ __align__(16) float attn_lds[NT * Hh * Nn];
    __shared__ __align__(16) float g_lds[NT * Cc];

    const int tid = threadIdx.x;
    const int blk = blockIdx.x;
    const int b   = blk / WT;
    const int tau = blk % WT;
    const int w   = W0 + tau;

    for (int idx = tid; idx < Nn * FIN; idx += 256) {
        const int n = idx >> 6, f = idx & 63;
        x_lds[idx] = x[((b * Nn + n) * Ww + w) * FIN + f];
    }
    __syncthreads();

    {
        const int q   = tid & 63;
        const int nh  = tid >> 6;
        const int co0 = 2 * q, co1 = co0 + 1;
        float w0[FIN], w1[FIN];
        {
            const float4* wr0 = (const float4*)(gat_w + co0 * FIN);
            const float4* wr1 = (const float4*)(gat_w + co1 * FIN);
#pragma unroll
            for (int i = 0; i < FIN / 4; ++i) {
                ((float4*)w0)[i] = wr0[i];
                ((float4*)w1)[i] = wr1[i];
            }
        }
        const float as0 = a_src[co0], as1 = a_src[co1];
        const float ad0 = a_dst[co0], ad1 = a_dst[co1];
        for (int n = nh; n < Nn; n += 4) {
            const float4* xr = (const float4*)(x_lds + n * FIN);
            float a0 = 0.f, a1 = 0.f;
#pragma unroll
            for (int i = 0; i < FIN / 4; ++i) {
                const float4 xv = xr[i];
                a0 += xv.x * w0[4*i] + xv.y * w0[4*i+1] + xv.z * w0[4*i+2] + xv.w * w0[4*i+3];
                a1 += xv.x * w1[4*i] + xv.y * w1[4*i+1] + xv.z * w1[4*i+2] + xv.w * w1[4*i+3];
            }
            *(float2*)(h_lds + n * Cc + co0) = make_float2(a0, a1);
            float es = a0 * as0 + a1 * as1;
            float ed = a0 * ad0 + a1 * ad1;
#pragma unroll
            for (int off = 1; off < 16; off <<= 1) {
                es += __shfl_xor(es, off, 16);
                ed += __shfl_xor(ed, off, 16);
            }
            if ((q & 15) == 0) {
                const int head = q >> 4;
                e_lds[n * Hh + head]           = es;
                e_lds[Nn * Hh + n * Hh + head] = ed;
            }
        }
    }
    __syncthreads();

    if (tid < NT * Hh) {
        const int n  = tid >> 2;
        const int hh = tid & 3;
        const float es = e_lds[n * Hh + hh];
        float sc[Nn];
        float mx = -1e30f;
#pragma unroll
        for (int j = 0; j < Nn; ++j) {
            float s = es + e_lds[Nn * Hh + j * Hh + hh];
            s = (s > 0.f) ? s : 0.2f * s;
            if (adj[n * Nn + j] == 0.0f) s = -1e9f;
            sc[j] = s;
            mx = fmaxf(mx, s);
        }
        float sum = 0.f;
#pragma unroll
        for (int j = 0; j < Nn; ++j) { const float p = expf(sc[j] - mx); sc[j] = p; sum += p; }
        const float inv = 1.0f / sum;
#pragma unroll
        for (int j = 0; j < Nn; ++j)
            attn_lds[(n * Hh + hh) * Nn + j] = sc[j] * inv;
    }
    __syncthreads();

    for (int idx = tid; idx < NT * Cc; idx += 256) {
        const int n  = idx >> 7;
        const int c  = idx & 127;
        const int hh = c >> 5;
        const float* ap = attn_lds + (n * Hh + hh) * Nn;
        float acc = 0.f;
#pragma unroll
        for (int j = 0; j < Nn; ++j)
            acc += ap[j] * h_lds[j * Cc + c];
        g_lds[idx] = acc;
    }
    __syncthreads();

    if (tid < NT * 32) {
        const int n = tid >> 5, lane = tid & 31;
        const float4 v = ((const float4*)(g_lds + n * Cc))[lane];
        float s  = v.x + v.y + v.z + v.w;
        float sq = v.x*v.x + v.y*v.y + v.z*v.z + v.w*v.w;
#pragma unroll
        for (int off = 16; off; off >>= 1) {
            s  += __shfl_xor(s, off, 32);
            sq += __shfl_xor(sq, off, 32);
        }
        const float mu   = s * (1.0f / Cc);
        const float rstd = rsqrtf(sq * (1.0f / Cc) - mu * mu + 1e-5f);
        const float4 gg = ((const float4*)ln_g)[lane];
        const float4 bb = ((const float4*)ln_b)[lane];
        float o0 = (v.x - mu) * rstd * gg.x + bb.x;
        float o1 = (v.y - mu) * rstd * gg.y + bb.y;
        float o2 = (v.z - mu) * rstd * gg.z + bb.z;
        float o3 = (v.w - mu) * rstd * gg.w + bb.w;
        const int r = b * NT + n;
        ushort4 uh, ul;
        split_bf16(o0, uh.x, ul.x);
        split_bf16(o1, uh.y, ul.y);
        split_bf16(o2, uh.z, ul.z);
        split_bf16(o3, uh.w, ul.w);
        const size_t off = (size_t)(r * WT + tau) * Cc + lane * 4;
        *(ushort4*)(seq_hi + off) = uh;
        *(ushort4*)(seq_lo + off) = ul;
    }
}

// ---------------------------------------------------------------------------
// Kernel 2: per row r: TCN via split-bf16 MFMA (32x32x16), all in LDS.
// 8 waves = 2 M-tiles x 4 N-tiles. 3 MFMAs/kstep: ah*bh + al*bh + ah*bl.
// ---------------------------------------------------------------------------
__device__ __forceinline__ void conv_mfma(
    const ushort* in_hi, const ushort* in_lo,
    ushort* out_hi, ushort* out_lo,
    const ushort* __restrict__ wbh, const ushort* __restrict__ wbl,  // phase base
    const float* __restrict__ psb, const float* __restrict__ pss,
    const float* __restrict__ psh,                                   // phase base
    const int tau0, const int d, const int mt, const int nt,
    const int lane, const bool residual)
{
    const int m  = lane & 31;
    const int q2 = lane >> 5;
    const int co = nt * 32 + m;

    f32x16 acc;
#pragma unroll
    for (int i = 0; i < 16; ++i) acc[i] = 0.f;

    const int mbase = mt * 32 + m;
    for (int ks = 0; ks < 24; ++ks) {
        const int kk  = ks >> 3;
        const int ci0 = ((ks & 7) << 4) + (q2 << 3);
        int rowA = mbase - (2 - kk) * d;
        rowA = rowA < 0 ? 0 : rowA;           // clamped rows are discarded rows
        const short8 ah = *(const short8*)(in_hi + rowA * RS + ci0);
        const short8 al = *(const short8*)(in_lo + rowA * RS + ci0);
        const size_t wo = ((size_t)(nt * 24 + ks) * 64 + lane) * 8;
        const short8 bh = *(const short8*)(wbh + wo);
        const short8 bl = *(const short8*)(wbl + wo);
        acc = __builtin_amdgcn_mfma_f32_32x32x16_bf16(ah, bh, acc, 0, 0, 0);
        acc = __builtin_amdgcn_mfma_f32_32x32x16_bf16(al, bh, acc, 0, 0, 0);
        acc = __builtin_amdgcn_mfma_f32_32x32x16_bf16(ah, bl, acc, 0, 0, 0);
    }

    const float bsv = psb[co], scv = pss[co], shv = psh[co];
#pragma unroll
    for (int reg = 0; reg < 16; ++reg) {
        const int row = (reg & 3) + 8 * (reg >> 2) + 4 * q2;
        const int tau = mt * 32 + row;
        if (tau >= tau0 && tau <= 60) {
            float v = (acc[reg] + bsv) * scv + shv;
            v = gelu_exact(v);
            const int off = tau * RS + co;
            if (residual) {
                const float rc = b2f(out_hi[off]) + b2f(out_lo[off]);
                v = gelu_exact(v + rc);
            }
            ushort uh, ul; split_bf16(v, uh, ul);
            out_hi[off] = uh; out_lo[off] = ul;
        }
    }
}

__global__ __launch_bounds__(512, 4) void tcn_head_kernel(
    const char* __restrict__ ws,
    const float* __restrict__ f1w, const float* __restrict__ f1b,
    const float* __restrict__ f2w, const float* __restrict__ f2b,
    float* __restrict__ out)
{
    __shared__ __align__(16) ushort cur_hi[64 * RS];
    __shared__ __align__(16) ushort cur_lo[64 * RS];
    __shared__ __align__(16) ushort o1_hi [64 * RS];
    __shared__ __align__(16) ushort o1_lo [64 * RS];
    __shared__ float red[FC];

    const int tid = threadIdx.x;
    const int r   = blockIdx.x;

    const ushort* seq_hi = (const ushort*)(ws + SEQHI_OFF);
    const ushort* seq_lo = (const ushort*)(ws + SEQLO_OFF);
    const ushort* WBH    = (const ushort*)(ws + WBH_OFF);
    const ushort* WBL    = (const ushort*)(ws + WBL_OFF);
    const float*  PSB    = (const float*)(ws + PSB_OFF);
    const float*  PSS    = (const float*)(ws + PSS_OFF);
    const float*  PSH    = (const float*)(ws + PSH_OFF);

    // stage seq row (61 x 128 bf16 hi/lo) into padded LDS
    {
        const size_t base = (size_t)r * WT * Cc;
        for (int i = tid; i < WT * 16; i += 512) {
            const int row = i >> 4, c = i & 15;
            *(uint4*)(cur_hi + row * RS + c * 8) =
                *(const uint4*)(seq_hi + base + row * Cc + c * 8);
            *(uint4*)(cur_lo + row * RS + c * 8) =
                *(const uint4*)(seq_lo + base + row * Cc + c * 8);
        }
    }
    __syncthreads();

    const int wave = tid >> 6;
    const int lane = tid & 63;
    const int nt   = wave & 3;
    const int mt   = wave >> 2;

    const int tau0_1[4] = {2, 8, 20, 44};
    const int tau0_2[4] = {4, 12, 28, 60};

#pragma unroll
    for (int l = 0; l < 4; ++l) {
        const int d  = 1 << l;
        const int p1 = 2 * l, p2 = 2 * l + 1;
        conv_mfma(cur_hi, cur_lo, o1_hi, o1_lo,
                  WBH + (size_t)p1 * WPHASE_US, WBL + (size_t)p1 * WPHASE_US,
                  PSB + p1 * Cc, PSS + p1 * Cc, PSH + p1 * Cc,
                  tau0_1[l], d, mt, nt, lane, false);
        __syncthreads();
        conv_mfma(o1_hi, o1_lo, cur_hi, cur_lo,
                  WBH + (size_t)p2 * WPHASE_US, WBL + (size_t)p2 * WPHASE_US,
                  PSB + p2 * Cc, PSS + p2 * Cc, PSH + p2 * Cc,
                  tau0_2[l], d, mt, nt, lane, true);
        __syncthreads();
    }

    // ---- fused head on cur[60][:] ----
    if (tid < FC) {
        const float4* wr = (const float4*)(f1w + tid * Cc);
        float acc = 0.f;
#pragma unroll
        for (int i = 0; i < Cc / 4; ++i) {
            const float4 wv = wr[i];
            const int ci = i * 4;
            acc += wv.x * (b2f(cur_hi[60 * RS + ci + 0]) + b2f(cur_lo[60 * RS + ci + 0]))
                 + wv.y * (b2f(cur_hi[60 * RS + ci + 1]) + b2f(cur_lo[60 * RS + ci + 1]))
                 + wv.z * (b2f(cur_hi[60 * RS + ci + 2]) + b2f(cur_lo[60 * RS + ci + 2]))
                 + wv.w * (b2f(cur_hi[60 * RS + ci + 3]) + b2f(cur_lo[60 * RS + ci + 3]));
        }
        red[tid] = gelu_exact(acc + f1b[tid]) * f2w[tid];
    }
    __syncthreads();
    if (tid < 64) {
        float v = red[tid] + red[tid + 64];
#pragma unroll
        for (int off = 32; off; off >>= 1) v += __shfl_xor(v, off, 64);
        if (tid == 0) out[r] = v + f2b[0];
    }
}

// ---------------------------------------------------------------------------
extern "C" void kernel_launch(void* const* d_in, const int* in_sizes, int n_in,
                              void* d_out, int out_size, void* d_ws, size_t ws_size,
                              hipStream_t stream) {
    const float* x     = (const float*)d_in[0];
    const float* adj   = (const float*)d_in[1];
    const float* gat_w = (const float*)d_in[2];
    const float* a_src = (const float*)d_in[3];
    const float* a_dst = (const float*)d_in[4];
    const float* ln_g  = (const float*)d_in[5];
    const float* ln_b  = (const float*)d_in[6];
    const float* c1w   = (const float*)d_in[7];
    const float* c1b   = (const float*)d_in[8];
    const float* c2w   = (const float*)d_in[9];
    const float* c2b   = (const float*)d_in[10];
    const float* bn1s  = (const float*)d_in[11];
    const float* bn1b  = (const float*)d_in[12];
    const float* bn1m  = (const float*)d_in[13];
    const float* bn1v  = (const float*)d_in[14];
    const float* bn2s  = (const float*)d_in[15];
    const float* bn2b  = (const float*)d_in[16];
    const float* bn2m  = (const float*)d_in[17];
    const float* bn2v  = (const float*)d_in[18];
    const float* f1w   = (const float*)d_in[19];
    const float* f1b   = (const float*)d_in[20];
    const float* f2w   = (const float*)d_in[21];
    const float* f2b   = (const float*)d_in[22];

    char* ws = (char*)d_ws;

    prep_kernel<<<193, 256, 0, stream>>>(c1w, c1b, c2w, c2b,
        bn1s, bn1b, bn1m, bn1v, bn2s, bn2b, bn2m, bn2v, ws);

    gat_ln_kernel<<<Bb * WT, 256, 0, stream>>>(
        x, adj, gat_w, a_src, a_dst, ln_g, ln_b,
        (ushort*)(ws + SEQHI_OFF), (ushort*)(ws + SEQLO_OFF));

    tcn_head_kernel<<<Bb * NT, 512, 0, stream>>>(
        ws, f1w, f1b, f2w, f2b, (float*)d_out);
}